// Round 1
// baseline (452.179 us; speedup 1.0000x reference)
//
#include <hip/hip_runtime.h>
#include <stdint.h>

#define GLOBAL_AS __attribute__((address_space(1)))
#define LDS_AS    __attribute__((address_space(3)))

typedef __attribute__((ext_vector_type(8))) short short8;
typedef __attribute__((ext_vector_type(4))) float f32x4;
typedef __attribute__((ext_vector_type(4))) float float4v;
typedef __attribute__((ext_vector_type(4))) unsigned short ushort4v;

static constexpr int Bc = 2;
static constexpr int Lc = 512;
static constexpr int Cc = 256;
static constexpr int Pc = 128;
static constexpr int NP = Pc * Cc;  // 32768: flattened (p,c) with c minor

__device__ __forceinline__ unsigned short f2bf(float x) {
  unsigned int u = __builtin_bit_cast(unsigned int, x);
  u += 0x7FFFu + ((u >> 16) & 1u);
  return (unsigned short)(u >> 16);
}

__device__ __forceinline__ void gload_lds16(const void* g, void* l) {
  __builtin_amdgcn_global_load_lds((const GLOBAL_AS unsigned int*)g,
                                   (LDS_AS unsigned int*)l, 16, 0, 0);
}

// ---- pre-pass: f32 -> bf16 copy of single_repr ----
__global__ void convert_s_kernel(const float* __restrict__ s,
                                 unsigned short* __restrict__ out) {
  const int idx = (blockIdx.x * 256 + threadIdx.x) * 4;
  float4v v = *(const float4v*)&s[idx];
  ushort4v o;
  #pragma unroll
  for (int i = 0; i < 4; ++i) o[i] = f2bf(v[i]);
  *(ushort4v*)&out[idx] = o;
}

// ---- pre-pass: w_outer [c][d][p] f32 -> wT [c][p][d] bf16 (one block per c) ----
__global__ void prep_w_kernel(const float* __restrict__ w,
                              unsigned short* __restrict__ wT) {
  __shared__ unsigned short lds[128 * 258];
  const int c = blockIdx.x;
  const int t = threadIdx.x;
  const float* wc = w + (size_t)c * (Cc * Pc);
  #pragma unroll 4
  for (int it = 0; it < 128; ++it) {
    const int idx = it * 256 + t;        // idx = d*128 + p
    const int d = idx >> 7, p = idx & 127;
    lds[p * 258 + d] = f2bf(wc[idx]);
  }
  __syncthreads();
  unsigned short* o = wT + (size_t)c * NP;
  #pragma unroll 4
  for (int it = 0; it < 128; ++it) {
    const int idx = it * 256 + t;        // idx = p*256 + d
    const int p = idx >> 8, d = idx & 255;
    o[idx] = lds[p * 258 + d];
  }
}

// ---- GEMM 1: tmpT[j][p*256+c] = sum_d s[b,j,d] * wT[c][p][d] ----
// m97 structure: 128x128 tile, BK=64, 4 waves, 16x16x32 bf16 MFMA
__global__ __launch_bounds__(256) void gemm1_kernel(
    const unsigned short* __restrict__ sbf,
    const unsigned short* __restrict__ wT,
    unsigned short* __restrict__ tmpT,
    int b) {
  __shared__ unsigned short As[128 * 64];
  __shared__ unsigned short Bs[128 * 64];
  const int tid = threadIdx.x;
  const int wave = tid >> 6, lane = tid & 63;
  const int n0 = blockIdx.x * 128;   // over (p,c) flat, 256 blocks
  const int j0 = blockIdx.y * 128;   // 4 blocks
  const int p_wg = n0 >> 8;          // fixed p for this WG's n-range
  const int c_base = n0 & 255;
  const unsigned short* sA = sbf + b * Lc * Cc;

  const int wr = wave >> 1, wcn = wave & 1;
  const int lr = lane & 15, lk = (lane >> 4) << 3;

  f32x4 acc[4][4];
  const f32x4 zero = {0.f, 0.f, 0.f, 0.f};
  #pragma unroll
  for (int m = 0; m < 4; ++m)
    #pragma unroll
    for (int n = 0; n < 4; ++n) acc[m][n] = zero;

  #pragma unroll 1
  for (int kt = 0; kt < 4; ++kt) {
    const int d0 = kt * 64;
    __syncthreads();
    #pragma unroll
    for (int op = 0; op < 4; ++op) {
      const int idx = op * 256 + tid;
      const int row = idx >> 3, col = (idx & 7) << 3;
      gload_lds16(&sA[(j0 + row) * Cc + d0 + col],
                  &As[(size_t)(op * 256 + wave * 64) * 8]);
    }
    #pragma unroll
    for (int op = 0; op < 4; ++op) {
      const int idx = op * 256 + tid;
      const int row = idx >> 3, col = (idx & 7) << 3;
      gload_lds16(&wT[(size_t)(((c_base + row) << 7) + p_wg) * 256 + d0 + col],
                  &Bs[(size_t)(op * 256 + wave * 64) * 8]);
    }
    __syncthreads();
    #pragma unroll
    for (int kk = 0; kk < 2; ++kk) {
      short8 af[4], bfr[4];
      #pragma unroll
      for (int m = 0; m < 4; ++m)
        af[m] = *(const short8*)&As[(wr * 64 + m * 16 + lr) * 64 + kk * 32 + lk];
      #pragma unroll
      for (int n = 0; n < 4; ++n)
        bfr[n] = *(const short8*)&Bs[(wcn * 64 + n * 16 + lr) * 64 + kk * 32 + lk];
      #pragma unroll
      for (int m = 0; m < 4; ++m)
        #pragma unroll
        for (int n = 0; n < 4; ++n)
          acc[m][n] = __builtin_amdgcn_mfma_f32_16x16x32_bf16(af[m], bfr[n], acc[m][n], 0, 0, 0);
    }
  }

  const int rb = wr * 64 + ((lane >> 4) << 2);
  const int cb = wcn * 64 + lr;
  #pragma unroll
  for (int m = 0; m < 4; ++m)
    #pragma unroll
    for (int q = 0; q < 4; ++q) {
      const int row = rb + m * 16 + q;
      unsigned short* dst = &tmpT[(size_t)(j0 + row) * NP + n0 + cb];
      #pragma unroll
      for (int n = 0; n < 4; ++n) dst[n * 16] = f2bf(acc[m][n][q]);
    }
}

// ---- GEMM 2 + epilogue: z[b,i,j,p] = sum_c s[b,i,c]*tmpT[j][p*256+c] ----
__global__ __launch_bounds__(256) void gemm2_kernel(
    const unsigned short* __restrict__ sbf,
    const unsigned short* __restrict__ tmpT,
    const float* __restrict__ pair_bias,
    const float* __restrict__ mask,
    const float* __restrict__ b_outer,
    const float* __restrict__ pos_embed,
    const float* __restrict__ w_bias,
    const float* __restrict__ b_bias,
    float* __restrict__ out,
    int b) {
  __shared__ unsigned short As[128 * 64];
  __shared__ unsigned short Bs[128 * 64];
  const int tid = threadIdx.x;
  const int wave = tid >> 6, lane = tid & 63;
  const int j = blockIdx.x;          // 512
  const int i0 = blockIdx.y * 128;   // 4
  const unsigned short* sA = sbf + b * Lc * Cc;
  const unsigned short* tB = tmpT + (size_t)j * NP;

  const int wr = wave >> 1, wcn = wave & 1;
  const int lr = lane & 15, lk = (lane >> 4) << 3;

  f32x4 acc[4][4];
  const f32x4 zero = {0.f, 0.f, 0.f, 0.f};
  #pragma unroll
  for (int m = 0; m < 4; ++m)
    #pragma unroll
    for (int n = 0; n < 4; ++n) acc[m][n] = zero;

  #pragma unroll 1
  for (int kt = 0; kt < 4; ++kt) {
    const int c0 = kt * 64;
    __syncthreads();
    #pragma unroll
    for (int op = 0; op < 4; ++op) {
      const int idx = op * 256 + tid;
      const int row = idx >> 3, col = (idx & 7) << 3;
      gload_lds16(&sA[(i0 + row) * Cc + c0 + col],
                  &As[(size_t)(op * 256 + wave * 64) * 8]);
    }
    #pragma unroll
    for (int op = 0; op < 4; ++op) {
      const int idx = op * 256 + tid;
      const int row = idx >> 3, col = (idx & 7) << 3;
      gload_lds16(&tB[row * 256 + c0 + col],
                  &Bs[(size_t)(op * 256 + wave * 64) * 8]);
    }
    __syncthreads();
    #pragma unroll
    for (int kk = 0; kk < 2; ++kk) {
      short8 af[4], bfr[4];
      #pragma unroll
      for (int m = 0; m < 4; ++m)
        af[m] = *(const short8*)&As[(wr * 64 + m * 16 + lr) * 64 + kk * 32 + lk];
      #pragma unroll
      for (int n = 0; n < 4; ++n)
        bfr[n] = *(const short8*)&Bs[(wcn * 64 + n * 16 + lr) * 64 + kk * 32 + lk];
      #pragma unroll
      for (int m = 0; m < 4; ++m)
        #pragma unroll
        for (int n = 0; n < 4; ++n)
          acc[m][n] = __builtin_amdgcn_mfma_f32_16x16x32_bf16(af[m], bfr[n], acc[m][n], 0, 0, 0);
    }
  }

  const int rb = wr * 64 + ((lane >> 4) << 2);
  const int cb = wcn * 64 + lr;
  const float mj = mask[b * Lc + j];
  #pragma unroll
  for (int m = 0; m < 4; ++m)
    #pragma unroll
    for (int q = 0; q < 4; ++q) {
      const int i = i0 + rb + m * 16 + q;
      const float mi = mask[b * Lc + i];
      const float sc = mi * mj;
      const size_t pbo = ((size_t)(b * Lc + i) * Lc + j) * 2;
      const float pb0 = pair_bias[pbo], pb1 = pair_bias[pbo + 1];
      int rel = i - j;
      rel = rel < -15 ? -15 : (rel > 15 ? 15 : rel);
      rel += 15;
      const float* pe = pos_embed + rel * Pc;
      float* dst = out + ((size_t)(b * Lc + i) * Lc + j) * Pc + cb;
      #pragma unroll
      for (int n = 0; n < 4; ++n) {
        const int p = cb + n * 16;
        float v = acc[m][n][q] + b_outer[p] + b_bias[p] +
                  pb0 * w_bias[p] + pb1 * w_bias[Pc + p] + pe[p];
        dst[n * 16] = v * sc;
      }
    }
}

extern "C" void kernel_launch(void* const* d_in, const int* in_sizes, int n_in,
                              void* d_out, int out_size, void* d_ws, size_t ws_size,
                              hipStream_t stream) {
  const float* s         = (const float*)d_in[0];
  const float* pair_bias = (const float*)d_in[1];
  const float* mask      = (const float*)d_in[2];
  const float* w_outer   = (const float*)d_in[3];
  const float* b_outer   = (const float*)d_in[4];
  const float* pos_embed = (const float*)d_in[5];
  const float* w_bias    = (const float*)d_in[6];
  const float* b_bias    = (const float*)d_in[7];
  float* out = (float*)d_out;

  unsigned char* ws = (unsigned char*)d_ws;
  unsigned short* s_bf = (unsigned short*)ws;                          // 512 KB
  unsigned short* wT   = (unsigned short*)(ws + (512u << 10));         // 16 MB
  unsigned short* tmpT = (unsigned short*)(ws + (512u << 10) + (16u << 20)); // 32 MB (per-b, reused)

  convert_s_kernel<<<256, 256, 0, stream>>>(s, s_bf);
  prep_w_kernel<<<256, 256, 0, stream>>>(w_outer, wT);

  for (int b = 0; b < Bc; ++b) {
    gemm1_kernel<<<dim3(256, 4), 256, 0, stream>>>(s_bf, wT, tmpT, b);
    gemm2_kernel<<<dim3(512, 4), 256, 0, stream>>>(s_bf, tmpT, pair_bias, mask,
                                                   b_outer, pos_embed, w_bias,
                                                   b_bias, out, b);
  }
}

// Round 2
// 438.102 us; speedup vs baseline: 1.0321x; 1.0321x over previous
//
#include <hip/hip_runtime.h>
#include <stdint.h>

#define GLOBAL_AS __attribute__((address_space(1)))
#define LDS_AS    __attribute__((address_space(3)))

typedef __attribute__((ext_vector_type(8))) short short8;
typedef __attribute__((ext_vector_type(4))) float f32x4;
typedef __attribute__((ext_vector_type(4))) float float4v;
typedef __attribute__((ext_vector_type(2))) float float2v;
typedef __attribute__((ext_vector_type(4))) unsigned short ushort4v;

static constexpr int Bc = 2;
static constexpr int Lc = 512;
static constexpr int Cc = 256;
static constexpr int Pc = 128;
static constexpr int NP = Pc * Cc;            // 32768 flat (p,c), c minor
static constexpr size_t TMPB = (size_t)Lc * NP;  // elems per batch of tmpT

__device__ __forceinline__ unsigned short f2bf(float x) {
  unsigned int u = __builtin_bit_cast(unsigned int, x);
  u += 0x7FFFu + ((u >> 16) & 1u);
  return (unsigned short)(u >> 16);
}

__device__ __forceinline__ void gload_lds16(const void* g, void* l) {
  __builtin_amdgcn_global_load_lds((const GLOBAL_AS unsigned int*)g,
                                   (LDS_AS unsigned int*)l, 16, 0, 0);
}

// ---- pre-pass: f32 -> bf16 copy of single_repr ----
__global__ void convert_s_kernel(const float* __restrict__ s,
                                 unsigned short* __restrict__ out) {
  const int idx = (blockIdx.x * 256 + threadIdx.x) * 4;
  float4v v = *(const float4v*)&s[idx];
  ushort4v o;
  #pragma unroll
  for (int i = 0; i < 4; ++i) o[i] = f2bf(v[i]);
  *(ushort4v*)&out[idx] = o;
}

// ---- pre-pass: w_outer [c][d][p] f32 -> wT [c][p][d] bf16 (one block per c) ----
__global__ void prep_w_kernel(const float* __restrict__ w,
                              unsigned short* __restrict__ wT) {
  __shared__ unsigned short lds[128 * 258];
  const int c = blockIdx.x;
  const int t = threadIdx.x;
  const float* wc = w + (size_t)c * (Cc * Pc);
  #pragma unroll 4
  for (int it = 0; it < 128; ++it) {
    const int idx = it * 256 + t;        // idx = d*128 + p
    const int d = idx >> 7, p = idx & 127;
    lds[p * 258 + d] = f2bf(wc[idx]);
  }
  __syncthreads();
  unsigned short* o = wT + (size_t)c * NP;
  #pragma unroll 4
  for (int it = 0; it < 128; ++it) {
    const int idx = it * 256 + t;        // idx = p*256 + d
    const int p = idx >> 8, d = idx & 255;
    o[idx] = lds[p * 258 + d];
  }
}

// ---- GEMM 1: tmpT[j][p*256+c] = sum_d s[b,j,d] * wT[c][p][d] ----
// Operand roles: A = wT rows (flat (p,c) -> D rows, c q-contiguous), B = s rows (j -> D cols)
__global__ __launch_bounds__(256) void gemm1_swapped_kernel(
    const unsigned short* __restrict__ sbf,
    const unsigned short* __restrict__ wT,
    unsigned short* __restrict__ tmpT,
    int b_base) {
  __shared__ unsigned short Ws[128 * 64];
  __shared__ unsigned short Ss[128 * 64];
  const int tid = threadIdx.x;
  const int wave = tid >> 6, lane = tid & 63;
  const int z = blockIdx.z;
  const int b = b_base + z;
  const int n0 = blockIdx.x * 128;   // flat (p,c): p = n0>>8 fixed, c_base = n0&255
  const int j0 = blockIdx.y * 128;
  const int p_wg = n0 >> 8;
  const int c_base = n0 & 255;
  const unsigned short* sB = sbf + b * Lc * Cc;
  unsigned short* tT = tmpT + (size_t)z * TMPB;

  const int wr = wave >> 1, wcn = wave & 1;
  const int lr = lane & 15, lk = (lane >> 4) << 3;

  f32x4 acc[4][4];
  const f32x4 zero = {0.f, 0.f, 0.f, 0.f};
  #pragma unroll
  for (int m = 0; m < 4; ++m)
    #pragma unroll
    for (int n = 0; n < 4; ++n) acc[m][n] = zero;

  #pragma unroll 1
  for (int kt = 0; kt < 4; ++kt) {
    const int d0 = kt * 64;
    __syncthreads();
    #pragma unroll
    for (int op = 0; op < 4; ++op) {
      const int idx = op * 256 + tid;
      const int row = idx >> 3, col = (idx & 7) << 3;
      gload_lds16(&wT[(size_t)((c_base + row) * 128 + p_wg) * 256 + d0 + col],
                  &Ws[(size_t)(op * 256 + wave * 64) * 8]);
    }
    #pragma unroll
    for (int op = 0; op < 4; ++op) {
      const int idx = op * 256 + tid;
      const int row = idx >> 3, col = (idx & 7) << 3;
      gload_lds16(&sB[(j0 + row) * Cc + d0 + col],
                  &Ss[(size_t)(op * 256 + wave * 64) * 8]);
    }
    __syncthreads();
    #pragma unroll
    for (int kk = 0; kk < 2; ++kk) {
      short8 aw[4], bs[4];
      #pragma unroll
      for (int m = 0; m < 4; ++m)
        aw[m] = *(const short8*)&Ws[(wr * 64 + m * 16 + lr) * 64 + kk * 32 + lk];
      #pragma unroll
      for (int n = 0; n < 4; ++n)
        bs[n] = *(const short8*)&Ss[(wcn * 64 + n * 16 + lr) * 64 + kk * 32 + lk];
      #pragma unroll
      for (int m = 0; m < 4; ++m)
        #pragma unroll
        for (int n = 0; n < 4; ++n)
          acc[m][n] = __builtin_amdgcn_mfma_f32_16x16x32_bf16(aw[m], bs[n], acc[m][n], 0, 0, 0);
    }
  }

  // D: row = flat-(p,c) local (q-contiguous over c), col = j
  const int rbase = wr * 64 + ((lane >> 4) << 2);
  #pragma unroll
  for (int n = 0; n < 4; ++n) {
    const int j = j0 + wcn * 64 + n * 16 + lr;
    unsigned short* dst = &tT[(size_t)j * NP + n0 + rbase];
    #pragma unroll
    for (int m = 0; m < 4; ++m) {
      ushort4v o;
      #pragma unroll
      for (int q = 0; q < 4; ++q) o[q] = f2bf(acc[m][n][q]);
      *(ushort4v*)&dst[m * 16] = o;
    }
  }
}

// ---- GEMM 2 + epilogue: z[b,i,j,p] = sum_c s[b,i,c]*tmpT[j][p*256+c] ----
// Operand roles: A = tmpT rows (p -> D rows, q-contiguous), B = s rows (i -> D cols)
__global__ __launch_bounds__(256) void gemm2_swapped_kernel(
    const unsigned short* __restrict__ sbf,
    const unsigned short* __restrict__ tmpT,
    const float* __restrict__ pair_bias,
    const float* __restrict__ mask,
    const float* __restrict__ b_outer,
    const float* __restrict__ pos_embed,
    const float* __restrict__ w_bias,
    const float* __restrict__ b_bias,
    float* __restrict__ out,
    int b_base) {
  __shared__ unsigned short Ts[128 * 64];
  __shared__ unsigned short Ss[128 * 64];
  const int tid = threadIdx.x;
  const int wave = tid >> 6, lane = tid & 63;
  const int z = blockIdx.z;
  const int b = b_base + z;
  const int j = blockIdx.x;          // 512
  const int i0 = blockIdx.y * 128;   // 4
  const unsigned short* sB = sbf + b * Lc * Cc;
  const unsigned short* tB = tmpT + (size_t)z * TMPB + (size_t)j * NP;

  const int wr = wave >> 1, wcn = wave & 1;
  const int lr = lane & 15, lk = (lane >> 4) << 3;

  f32x4 acc[4][4];
  const f32x4 zero = {0.f, 0.f, 0.f, 0.f};
  #pragma unroll
  for (int m = 0; m < 4; ++m)
    #pragma unroll
    for (int n = 0; n < 4; ++n) acc[m][n] = zero;

  #pragma unroll 1
  for (int kt = 0; kt < 4; ++kt) {
    const int c0 = kt * 64;
    __syncthreads();
    #pragma unroll
    for (int op = 0; op < 4; ++op) {
      const int idx = op * 256 + tid;
      const int row = idx >> 3, col = (idx & 7) << 3;
      gload_lds16(&tB[row * 256 + c0 + col],
                  &Ts[(size_t)(op * 256 + wave * 64) * 8]);
    }
    #pragma unroll
    for (int op = 0; op < 4; ++op) {
      const int idx = op * 256 + tid;
      const int row = idx >> 3, col = (idx & 7) << 3;
      gload_lds16(&sB[(i0 + row) * Cc + c0 + col],
                  &Ss[(size_t)(op * 256 + wave * 64) * 8]);
    }
    __syncthreads();
    #pragma unroll
    for (int kk = 0; kk < 2; ++kk) {
      short8 at[4], bi[4];
      #pragma unroll
      for (int m = 0; m < 4; ++m)
        at[m] = *(const short8*)&Ts[(wr * 64 + m * 16 + lr) * 64 + kk * 32 + lk];
      #pragma unroll
      for (int n = 0; n < 4; ++n)
        bi[n] = *(const short8*)&Ss[(wcn * 64 + n * 16 + lr) * 64 + kk * 32 + lk];
      #pragma unroll
      for (int m = 0; m < 4; ++m)
        #pragma unroll
        for (int n = 0; n < 4; ++n)
          acc[m][n] = __builtin_amdgcn_mfma_f32_16x16x32_bf16(at[m], bi[n], acc[m][n], 0, 0, 0);
    }
  }

  // D: row = p (q-contiguous), col = i
  const int pbase = wr * 64 + ((lane >> 4) << 2);
  const float mj = mask[b * Lc + j];

  // per-m p-vectors (hoisted)
  float4v bsum[4], wb0[4], wb1[4];
  #pragma unroll
  for (int m = 0; m < 4; ++m) {
    const int p = pbase + m * 16;
    bsum[m] = *(const float4v*)&b_outer[p] + *(const float4v*)&b_bias[p];
    wb0[m] = *(const float4v*)&w_bias[p];
    wb1[m] = *(const float4v*)&w_bias[Pc + p];
  }

  #pragma unroll
  for (int n = 0; n < 4; ++n) {
    const int i = i0 + wcn * 64 + n * 16 + lr;
    const float sc = mask[b * Lc + i] * mj;
    const size_t rowoff = (size_t)(b * Lc + i) * Lc + j;
    const float2v pb = *(const float2v*)&pair_bias[rowoff * 2];
    int rel = i - j;
    rel = rel < -15 ? -15 : (rel > 15 ? 15 : rel);
    rel += 15;
    const float* pe_row = pos_embed + rel * Pc;
    float* drow = out + rowoff * Pc;
    #pragma unroll
    for (int m = 0; m < 4; ++m) {
      const int p = pbase + m * 16;
      const float4v pe4 = *(const float4v*)&pe_row[p];
      float4v v = acc[m][n] + bsum[m] + pb[0] * wb0[m] + pb[1] * wb1[m] + pe4;
      *(float4v*)&drow[p] = v * sc;
    }
  }
}

extern "C" void kernel_launch(void* const* d_in, const int* in_sizes, int n_in,
                              void* d_out, int out_size, void* d_ws, size_t ws_size,
                              hipStream_t stream) {
  const float* s         = (const float*)d_in[0];
  const float* pair_bias = (const float*)d_in[1];
  const float* mask      = (const float*)d_in[2];
  const float* w_outer   = (const float*)d_in[3];
  const float* b_outer   = (const float*)d_in[4];
  const float* pos_embed = (const float*)d_in[5];
  const float* w_bias    = (const float*)d_in[6];
  const float* b_bias    = (const float*)d_in[7];
  float* out = (float*)d_out;

  unsigned char* ws = (unsigned char*)d_ws;
  unsigned short* s_bf = (unsigned short*)ws;                          // 512 KB
  unsigned short* wT   = (unsigned short*)(ws + (512u << 10));         // 16 MB
  unsigned short* tmpT = (unsigned short*)(ws + (512u << 10) + (16u << 20));

  const size_t need_batched = (512u << 10) + (16u << 20) + 2 * (TMPB * 2);
  const bool batched = ws_size >= need_batched;

  convert_s_kernel<<<256, 256, 0, stream>>>(s, s_bf);
  prep_w_kernel<<<256, 256, 0, stream>>>(w_outer, wT);

  if (batched) {
    gemm1_swapped_kernel<<<dim3(256, 4, 2), 256, 0, stream>>>(s_bf, wT, tmpT, 0);
    gemm2_swapped_kernel<<<dim3(512, 4, 2), 256, 0, stream>>>(
        s_bf, tmpT, pair_bias, mask, b_outer, pos_embed, w_bias, b_bias, out, 0);
  } else {
    for (int b = 0; b < Bc; ++b) {
      gemm1_swapped_kernel<<<dim3(256, 4, 1), 256, 0, stream>>>(s_bf, wT, tmpT, b);
      gemm2_swapped_kernel<<<dim3(512, 4, 1), 256, 0, stream>>>(
          s_bf, tmpT, pair_bias, mask, b_outer, pos_embed, w_bias, b_bias, out, b);
    }
  }
}

// Round 3
// 427.580 us; speedup vs baseline: 1.0575x; 1.0246x over previous
//
#include <hip/hip_runtime.h>
#include <stdint.h>

#define GLOBAL_AS __attribute__((address_space(1)))
#define LDS_AS    __attribute__((address_space(3)))

typedef __attribute__((ext_vector_type(8))) short short8;
typedef __attribute__((ext_vector_type(4))) float f32x4;
typedef __attribute__((ext_vector_type(4))) float float4v;
typedef __attribute__((ext_vector_type(2))) float float2v;
typedef __attribute__((ext_vector_type(4))) unsigned short ushort4v;

static constexpr int Bc = 2;
static constexpr int Lc = 512;
static constexpr int Cc = 256;
static constexpr int Pc = 128;
static constexpr int NP = Pc * Cc;               // 32768 per j: [p][c], c minor
static constexpr size_t TMPB = (size_t)Lc * NP;  // elems per batch of tmpT

__device__ __forceinline__ unsigned short f2bf(float x) {
  unsigned int u = __builtin_bit_cast(unsigned int, x);
  u += 0x7FFFu + ((u >> 16) & 1u);
  return (unsigned short)(u >> 16);
}

__device__ __forceinline__ void gload_lds16(const void* g, void* l) {
  __builtin_amdgcn_global_load_lds((const GLOBAL_AS unsigned int*)g,
                                   (LDS_AS unsigned int*)l, 16, 0, 0);
}

// ---- pre-pass: f32 -> bf16 copy of single_repr ----
__global__ void convert_s_kernel(const float* __restrict__ s,
                                 unsigned short* __restrict__ out) {
  const int idx = (blockIdx.x * 256 + threadIdx.x) * 4;
  float4v v = *(const float4v*)&s[idx];
  ushort4v o;
  #pragma unroll
  for (int i = 0; i < 4; ++i) o[i] = f2bf(v[i]);
  *(ushort4v*)&out[idx] = o;
}

// ---- pre-pass: w_outer [c][d][p] f32 -> wA [p][c][d] bf16 (one block per c) ----
__global__ void prep_w_kernel(const float* __restrict__ w,
                              unsigned short* __restrict__ wA) {
  __shared__ unsigned short lds[128 * 258];
  const int c = blockIdx.x;
  const int t = threadIdx.x;
  const float* wc = w + (size_t)c * (Cc * Pc);
  #pragma unroll 4
  for (int it = 0; it < 128; ++it) {
    const int idx = it * 256 + t;        // idx = d*128 + p
    const int d = idx >> 7, p = idx & 127;
    lds[p * 258 + d] = f2bf(wc[idx]);
  }
  __syncthreads();
  #pragma unroll 4
  for (int it = 0; it < 128; ++it) {
    const int idx = it * 256 + t;        // idx = p*256 + d
    const int p = idx >> 8, d = idx & 255;
    wA[(size_t)p * 65536 + (size_t)c * 256 + d] = lds[p * 258 + d];
  }
}

// ---- shared 256x256-tile, BK=64, K=256, 8-wave, double-buffered 2-phase core ----
// gA/gB: row-major bf16, row stride 256 elems, 256 rows each. acc[8][4] out.
__device__ __forceinline__ void run_gemm_k256(
    const unsigned short* __restrict__ gA,
    const unsigned short* __restrict__ gB,
    unsigned short (&As)[2][256 * 64],
    unsigned short (&Bs)[2][256 * 64],
    const int tid, const int wave, const int wr, const int wc,
    const int lr, const int lk,
    f32x4 (&acc)[8][4]) {
  auto stage = [&](int sel, int t) {
    const int k0 = t * 64;
    #pragma unroll
    for (int r = 0; r < 4; ++r) {
      const int idx = r * 512 + tid;
      const int row = idx >> 3, col = (idx & 7) << 3;
      gload_lds16(&gA[(size_t)row * 256 + k0 + col],
                  &As[sel][(size_t)(r * 512 + wave * 64) * 8]);
    }
    #pragma unroll
    for (int r = 0; r < 4; ++r) {
      const int idx = r * 512 + tid;
      const int row = idx >> 3, col = (idx & 7) << 3;
      gload_lds16(&gB[(size_t)row * 256 + k0 + col],
                  &Bs[sel][(size_t)(r * 512 + wave * 64) * 8]);
    }
  };

  stage(0, 0);
  __syncthreads();
  #pragma unroll
  for (int t = 0; t < 4; ++t) {
    const int cur = t & 1;
    if (t < 3) stage(cur ^ 1, t + 1);   // prefetch next K-tile into other buffer
    #pragma unroll
    for (int kk = 0; kk < 2; ++kk) {
      short8 a[8], b[4];
      #pragma unroll
      for (int m = 0; m < 8; ++m)
        a[m] = *(const short8*)&As[cur][(wr * 128 + m * 16 + lr) * 64 + kk * 32 + lk];
      #pragma unroll
      for (int n = 0; n < 4; ++n)
        b[n] = *(const short8*)&Bs[cur][(wc * 64 + n * 16 + lr) * 64 + kk * 32 + lk];
      #pragma unroll
      for (int m = 0; m < 8; ++m)
        #pragma unroll
        for (int n = 0; n < 4; ++n)
          acc[m][n] = __builtin_amdgcn_mfma_f32_16x16x32_bf16(a[m], b[n], acc[m][n], 0, 0, 0);
    }
    __syncthreads();   // drains prefetch vmcnt + syncs LDS reuse
  }
}

// ---- GEMM 1: tmpT[z][j][p][c] = sum_d s[z,j,d] * wA[p][c][d] ----
// D rows = flat (p-fixed, c) [M], cols = j [N]
__global__ __launch_bounds__(512, 2) void gemm1_k(
    const unsigned short* __restrict__ sbf,
    const unsigned short* __restrict__ wA,
    unsigned short* __restrict__ tmpT) {
  __shared__ unsigned short As[2][256 * 64];
  __shared__ unsigned short Bs[2][256 * 64];
  const int tid = threadIdx.x;
  const int wave = tid >> 6, lane = tid & 63;
  const int wr = wave >> 2, wc = wave & 3;
  const int lr = lane & 15, lk = (lane >> 4) << 3;
  const int p = blockIdx.x;            // 128 M-tiles: one p each (256 c rows)
  const int j0 = blockIdx.y * 256;     // 2 N-tiles
  const int z = blockIdx.z;            // batch

  const unsigned short* gA = wA + (size_t)p * 65536;
  const unsigned short* gB = sbf + (size_t)z * Lc * Cc + (size_t)j0 * 256;

  f32x4 acc[8][4];
  const f32x4 zero = {0.f, 0.f, 0.f, 0.f};
  #pragma unroll
  for (int m = 0; m < 8; ++m)
    #pragma unroll
    for (int n = 0; n < 4; ++n) acc[m][n] = zero;

  run_gemm_k256(gA, gB, As, Bs, tid, wave, wr, wc, lr, lk, acc);

  unsigned short* tT = tmpT + (size_t)z * TMPB;
  const int cq = wr * 128 + ((lane >> 4) << 2);   // c base (+ m*16 + q)
  #pragma unroll
  for (int n = 0; n < 4; ++n) {
    const int j = j0 + wc * 64 + n * 16 + lr;
    unsigned short* dst = tT + (size_t)j * NP + p * 256 + cq;
    #pragma unroll
    for (int m = 0; m < 8; ++m) {
      ushort4v o;
      #pragma unroll
      for (int q = 0; q < 4; ++q) o[q] = f2bf(acc[m][n][q]);
      *(ushort4v*)&dst[m * 16] = o;
    }
  }
}

// ---- GEMM 2 + epilogue: out[z,i,j,p] = sum_c s[z,i,c]*tmpT[z][j][p][c] ----
// D rows = flat (j,p) [M], cols = i [N]
__global__ __launch_bounds__(512, 2) void gemm2_k(
    const unsigned short* __restrict__ sbf,
    const unsigned short* __restrict__ tmpT,
    const float* __restrict__ pair_bias,
    const float* __restrict__ mask,
    const float* __restrict__ b_outer,
    const float* __restrict__ pos_embed,
    const float* __restrict__ w_bias,
    const float* __restrict__ b_bias,
    float* __restrict__ out) {
  __shared__ unsigned short As[2][256 * 64];
  __shared__ unsigned short Bs[2][256 * 64];
  const int tid = threadIdx.x;
  const int wave = tid >> 6, lane = tid & 63;
  const int wr = wave >> 2, wc = wave & 3;
  const int lr = lane & 15, lk = (lane >> 4) << 3;
  const int jt = blockIdx.x;           // 256 M-tiles: 2 j's each
  const int i0 = blockIdx.y * 256;     // 2 N-tiles
  const int z = blockIdx.z;            // batch

  const unsigned short* gA = tmpT + (size_t)z * TMPB + (size_t)jt * 65536;
  const unsigned short* gB = sbf + (size_t)z * Lc * Cc + (size_t)i0 * 256;

  f32x4 acc[8][4];
  const f32x4 zero = {0.f, 0.f, 0.f, 0.f};
  #pragma unroll
  for (int m = 0; m < 8; ++m)
    #pragma unroll
    for (int n = 0; n < 4; ++n) acc[m][n] = zero;

  run_gemm_k256(gA, gB, As, Bs, tid, wave, wr, wc, lr, lk, acc);

  // epilogue: wave owns one j (= jt*2 + wr), all 128 p, 64 i
  const int j = jt * 2 + wr;
  const int pq = (lane >> 4) << 2;
  const float mj = mask[z * Lc + j];

  float4v base8[8];
  #pragma unroll
  for (int m = 0; m < 8; ++m) {
    const int pp = m * 16 + pq;
    base8[m] = *(const float4v*)&b_outer[pp] + *(const float4v*)&b_bias[pp];
  }

  #pragma unroll
  for (int n = 0; n < 4; ++n) {
    const int i = i0 + wc * 64 + n * 16 + lr;
    const float sc = mask[z * Lc + i] * mj;
    const size_t rowoff = ((size_t)(z * Lc + i)) * Lc + j;
    const float2v pb = *(const float2v*)&pair_bias[rowoff * 2];
    int rel = i - j;
    rel = rel < -15 ? -15 : (rel > 15 ? 15 : rel);
    rel += 15;
    const float* pe_row = pos_embed + rel * Pc;
    float* drow = out + rowoff * Pc;
    #pragma unroll
    for (int m = 0; m < 8; ++m) {
      const int pp = m * 16 + pq;
      const float4v wb0 = *(const float4v*)&w_bias[pp];
      const float4v wb1 = *(const float4v*)&w_bias[Pc + pp];
      const float4v pe4 = *(const float4v*)&pe_row[pp];
      float4v v = acc[m][n] + base8[m] + pb[0] * wb0 + pb[1] * wb1 + pe4;
      *(float4v*)&drow[pp] = v * sc;
    }
  }
}

extern "C" void kernel_launch(void* const* d_in, const int* in_sizes, int n_in,
                              void* d_out, int out_size, void* d_ws, size_t ws_size,
                              hipStream_t stream) {
  const float* s         = (const float*)d_in[0];
  const float* pair_bias = (const float*)d_in[1];
  const float* mask      = (const float*)d_in[2];
  const float* w_outer   = (const float*)d_in[3];
  const float* b_outer   = (const float*)d_in[4];
  const float* pos_embed = (const float*)d_in[5];
  const float* w_bias    = (const float*)d_in[6];
  const float* b_bias    = (const float*)d_in[7];
  float* out = (float*)d_out;

  unsigned char* ws = (unsigned char*)d_ws;
  unsigned short* s_bf = (unsigned short*)ws;                          // 512 KB
  unsigned short* wA   = (unsigned short*)(ws + (512u << 10));         // 16 MB
  unsigned short* tmpT = (unsigned short*)(ws + (512u << 10) + (16u << 20)); // 2x33.5 MB

  convert_s_kernel<<<256, 256, 0, stream>>>(s, s_bf);
  prep_w_kernel<<<256, 256, 0, stream>>>(w_outer, wA);
  gemm1_k<<<dim3(128, 2, 2), 512, 0, stream>>>(s_bf, wA, tmpT);
  gemm2_k<<<dim3(256, 2, 2), 512, 0, stream>>>(s_bf, tmpT, pair_bias, mask,
                                               b_outer, pos_embed, w_bias,
                                               b_bias, out);
}